// Round 7
// baseline (782.166 us; speedup 1.0000x reference)
//
#include <hip/hip_runtime.h>

typedef __attribute__((ext_vector_type(4))) float  f32x4;
typedef __attribute__((ext_vector_type(4))) __bf16 bf16x4;
typedef __attribute__((ext_vector_type(8))) __bf16 bf16x8;

#define MFMA16 __builtin_amdgcn_mfma_f32_16x16x32_bf16
#define TINY_THR 4.8789098e-18f
#define XOUT_N ((size_t)4096 * 64 * 45)

__device__ __forceinline__ void bar_lds() {
  asm volatile("s_waitcnt lgkmcnt(0)\n\ts_barrier" ::: "memory");
}
__device__ __forceinline__ void split_bf16(float v, __bf16& h, __bf16& l) {
  h = (__bf16)v; l = (__bf16)(v - (float)h);
}
__device__ __forceinline__ void gll16(const void* g, void* l) {
  __builtin_amdgcn_global_load_lds(
      (const __attribute__((address_space(1))) void*)g,
      (__attribute__((address_space(3))) void*)l, 16, 0, 0);
}

// Packed+swizzled bf16 tile [rows][64 cols], 128 B/row, 8 blocks of 16 B.
__device__ __forceinline__ int pk_off(int row, int col) {
  const int kk = col >> 5, rem = col & 31;
  const int half = rem >> 4, qq = (rem >> 2) & 3, j = rem & 3;
  return row * 128 + ((((kk << 2) | qq) ^ (row & 7)) << 4) + half * 8 + j * 2;
}
__device__ __forceinline__ bf16x8 frag_pk(const char* base, int row, int kk, int qq) {
  return *(const bf16x8*)(base + row * 128 + ((((kk << 2) | qq) ^ (row & 7)) << 4));
}

// ---------------------------------------------------------------------------
// Kernel 0: prepack W_fc1 (unchanged)
// ---------------------------------------------------------------------------
__global__ void k_prepW(const float* __restrict__ Wfc, __bf16* __restrict__ Wpk) {
  const int idx = blockIdx.x * 256 + threadIdx.x;  // 32768 total
  const float v = Wfc[idx];
  __bf16 h, l; split_bf16(v, h, l);
  const int row = idx >> 9, k = idx & 511;
  const int c = k >> 6, kl = k & 63;
  const int kk = kl >> 5, rem = kl & 31;
  const int half = rem >> 4, q = (rem >> 2) & 3, j = rem & 3;
  const int blk = ((kk << 2) | q) ^ (row & 7);
  const int pos = c * 8192 + row * 64 + blk * 8 + half * 4 + j;
  Wpk[pos] = h;
  Wpk[pos + 4096] = l;
}

// ---------------------------------------------------------------------------
// Kernel 1: enc = relu(x . W_fc1^T + b). Same main loop as R4; epilogue now
// LDS-bounce transposed so enc writes are 4x dwordx4 coalesced (256B rows)
// instead of 16 scattered dwords (64B segments, ~50% write efficiency).
// ---------------------------------------------------------------------------
__global__ __launch_bounds__(256, 2) void k_encgemm(
    const float* __restrict__ x, const __bf16* __restrict__ Wpk,
    const float* __restrict__ bfc, float* __restrict__ enc) {
  __shared__ __attribute__((aligned(16))) char sm[65536];
  const int tid  = threadIdx.x;
  const int lane = tid & 63;
  const int wv   = tid >> 6;
  const int fr   = lane & 15;
  const int q    = lane >> 4;
  const int b    = blockIdx.x;

  auto stage = [&](int c, int buf) {
    char* xbase = sm + buf * 16384;
    char* wbase = sm + 32768 + buf * 16384;
    #pragma unroll
    for (int i = 0; i < 4; ++i) {
      const int B   = wv * 256 + i * 64 + lane;
      const int row = B >> 4, blk = B & 15;
      const int bp  = blk ^ (row & 15);
      const int colb = ((bp >> 3) << 5) | ((bp & 1) << 4) | (((bp >> 1) & 3) << 2);
      const float* src = x + ((size_t)b * 64 + row) * 512 + c * 64 + colb;
      gll16(src, xbase + wv * 4096 + i * 1024);
    }
    #pragma unroll
    for (int i = 0; i < 4; ++i) {
      const __bf16* srcw = Wpk + c * 8192 + wv * 2048 + i * 512 + lane * 8;
      gll16(srcw, wbase + wv * 4096 + i * 1024);
    }
  };

  f32x4 acc[4];
  #pragma unroll
  for (int nt = 0; nt < 4; ++nt) acc[nt] = (f32x4){0.f, 0.f, 0.f, 0.f};

  stage(0, 0);
  int buf = 0;
  for (int c = 0; c < 8; ++c) {
    if (c < 7) {
      stage(c + 1, buf ^ 1);
      asm volatile("s_waitcnt vmcnt(8)\n\ts_barrier" ::: "memory");
    } else {
      asm volatile("s_waitcnt vmcnt(0)\n\ts_barrier" ::: "memory");
    }
    const char* xbase = sm + buf * 16384;
    const char* wbase = sm + 32768 + buf * 16384;
    const int arow = wv * 16 + fr;
    bf16x8 Ah[2], Al[2];
    #pragma unroll
    for (int kk = 0; kk < 2; ++kk) {
      f32x4 u0 = *(const f32x4*)(xbase + arow * 256 + (((kk * 8 + q * 2 + 0) ^ (arow & 15)) << 4));
      f32x4 u1 = *(const f32x4*)(xbase + arow * 256 + (((kk * 8 + q * 2 + 1) ^ (arow & 15)) << 4));
      #pragma unroll
      for (int j = 0; j < 4; ++j) {
        __bf16 h, l;
        split_bf16(u0[j], h, l); Ah[kk][j] = h;     Al[kk][j] = l;
        split_bf16(u1[j], h, l); Ah[kk][4 + j] = h; Al[kk][4 + j] = l;
      }
    }
    #pragma unroll
    for (int nt = 0; nt < 4; ++nt) {
      const int brow = nt * 16 + fr;
      #pragma unroll
      for (int kk = 0; kk < 2; ++kk) {
        bf16x8 Bh = frag_pk(wbase, brow, kk, q);
        bf16x8 Bl = frag_pk(wbase + 8192, brow, kk, q);
        acc[nt] = MFMA16(Ah[kk], Bh, acc[nt], 0, 0, 0);
        acc[nt] = MFMA16(Ah[kk], Bl, acc[nt], 0, 0, 0);
        acc[nt] = MFMA16(Al[kk], Bh, acc[nt], 0, 0, 0);
      }
    }
    bar_lds();
    buf ^= 1;
  }
  // epilogue: bounce through LDS (wave-private region, free after final bar)
  // so global stores are 256B-contiguous per row.
  float* ep = (float*)(sm + wv * 4352);  // 16 rows x 68 f32 (272B, 16B-align)
  #pragma unroll
  for (int nt = 0; nt < 4; ++nt) {
    const int o = nt * 16 + fr;
    const float bb = bfc[o];
    #pragma unroll
    for (int e = 0; e < 4; ++e)
      ep[(q * 4 + e) * 68 + o] = fmaxf(acc[nt][e] + bb, 0.f);
  }
  asm volatile("s_waitcnt lgkmcnt(0)" ::: "memory");
  #pragma unroll
  for (int r2 = 0; r2 < 4; ++r2) {
    const int row = (lane >> 4) + 4 * r2;  // 4 rows per instr, 16 lanes each
    const int cg  = lane & 15;
    f32x4 v = *(const f32x4*)(ep + row * 68 + cg * 4);
    *(f32x4*)(enc + ((size_t)b * 64 + wv * 16 + row) * 64 + cg * 4) = v;
  }
}

// ---------------------------------------------------------------------------
// Kernel 2: fused GRU scan — R4-exact logic, wrapped in a REPS loop.
// REPS=1: production. REPS=6: PMC-instrumentation duplicate (writes scratch,
// runs the full scan 6x so its ~670us dispatch lands in rocprof's top-5 and
// exposes VGPR_Count / Occupancy / VALUBusy / MfmaUtil / LDS_BANK_CONFLICT).
// ---------------------------------------------------------------------------
template <int REPS>
__global__ __launch_bounds__(512, 1) void k_scan(
    const float* __restrict__ enc, const float* __restrict__ h0g,
    const float* __restrict__ eps, const float* __restrict__ Wih,
    const float* __restrict__ Whh, const float* __restrict__ bih,
    const float* __restrict__ bhh, const float* __restrict__ Wout,
    const float* __restrict__ bout, float* __restrict__ xout,
    float* __restrict__ hout) {
  __shared__ __attribute__((aligned(16))) char sm[55808];
  char* const wst0 = sm;
  char* const wst1 = sm + 24576;

  const int tid  = threadIdx.x;
  const int lane = tid & 63;
  const int wv   = tid >> 6;
  const int fr   = lane & 15;
  const int q    = lane >> 4;
  const int bbase = blockIdx.x * 16;
  const bool isB = (wv < 4);
  const int aw  = wv - 4;
  const int at  = tid & 255;
  const int sb  = at >> 4;
  const int sub = at & 15;
  const int so  = sub << 2;

  float biasNh = 0.f;
  int hcol = 0;
  float bR_ = 0.f, bZ_ = 0.f, bN_ = 0.f, boutv = 0.f, epsv = 0.f;
  if (isB) {
    hcol = wv * 16 + fr;
    biasNh = bhh[128 + hcol];
  } else {
    const int gc = aw * 16 + fr;
    bR_ = bih[gc] + bhh[gc];
    bZ_ = bih[64 + gc] + bhh[64 + gc];
    bN_ = bih[128 + gc];
    if (aw < 3 && gc < 45) boutv = bout[gc];
    epsv = eps[bbase + sb];
  }

  bf16x8 Fh[3][2], Fl[3][2];
  bf16x8 Fout[2][2];

  for (int idx = tid; idx < 192 * 64; idx += 512) {
    __bf16 h, l; split_bf16(Wih[idx], h, l);
    const int off = pk_off(idx >> 6, idx & 63);
    *(__bf16*)(wst0 + off) = h;
    *(__bf16*)(wst1 + off) = l;
  }
  bar_lds();
  if (!isB) {
    #pragma unroll
    for (int t3 = 0; t3 < 3; ++t3)
      #pragma unroll
      for (int kk = 0; kk < 2; ++kk) {
        const int row = (aw + 4 * t3) * 16 + fr;
        Fh[t3][kk] = frag_pk(wst0, row, kk, q);
        Fl[t3][kk] = frag_pk(wst1, row, kk, q);
      }
  }
  bar_lds();
  for (int idx = tid; idx < 192 * 64; idx += 512) {
    __bf16 h, l; split_bf16(Whh[idx], h, l);
    const int off = pk_off(idx >> 6, idx & 63);
    *(__bf16*)(wst0 + off) = h;
    *(__bf16*)(wst1 + off) = l;
  }
  bar_lds();
  if (isB) {
    #pragma unroll
    for (int t3 = 0; t3 < 3; ++t3)
      #pragma unroll
      for (int kk = 0; kk < 2; ++kk) {
        const int row = (wv + 4 * t3) * 16 + fr;
        Fh[t3][kk] = frag_pk(wst0, row, kk, q);
        Fl[t3][kk] = frag_pk(wst1, row, kk, q);
      }
  }
  bar_lds();
  for (int idx = tid; idx < 48 * 64; idx += 512) {
    float v = (idx < 45 * 64) ? Wout[idx] : 0.f;
    __bf16 h, l; split_bf16(v, h, l);
    const int off = pk_off(idx >> 6, idx & 63);
    *(__bf16*)(wst0 + off) = h;
    *(__bf16*)(wst1 + off) = l;
  }
  bar_lds();
  if (!isB && aw < 3) {
    #pragma unroll
    for (int kk = 0; kk < 2; ++kk) {
      const int row = aw * 16 + fr;
      Fout[kk][0] = frag_pk(wst0, row, kk, q);
      Fout[kk][1] = frag_pk(wst1, row, kk, q);
    }
  }
  bar_lds();  // wstage free -> runtime buffers live

  auto gate_mfma = [&](const char* s0, f32x4& a0, f32x4& a1, f32x4& a2) {
    const char* s1 = s0 + 2048;
    bf16x8 Sh[2], Sl[2];
    #pragma unroll
    for (int kk = 0; kk < 2; ++kk) {
      Sh[kk] = frag_pk(s0, fr, kk, q);
      Sl[kk] = frag_pk(s1, fr, kk, q);
    }
    __builtin_amdgcn_s_setprio(1);
    #pragma unroll
    for (int kk = 0; kk < 2; ++kk) {
      a0 = MFMA16(Sh[kk], Fh[0][kk], a0, 0, 0, 0);
      a0 = MFMA16(Sh[kk], Fl[0][kk], a0, 0, 0, 0);
      a0 = MFMA16(Sl[kk], Fh[0][kk], a0, 0, 0, 0);
      a1 = MFMA16(Sh[kk], Fh[1][kk], a1, 0, 0, 0);
      a1 = MFMA16(Sh[kk], Fl[1][kk], a1, 0, 0, 0);
      a1 = MFMA16(Sl[kk], Fh[1][kk], a1, 0, 0, 0);
      a2 = MFMA16(Sh[kk], Fh[2][kk], a2, 0, 0, 0);
      a2 = MFMA16(Sh[kk], Fl[2][kk], a2, 0, 0, 0);
      a2 = MFMA16(Sl[kk], Fh[2][kk], a2, 0, 0, 0);
    }
    __builtin_amdgcn_s_setprio(0);
  };
  auto put_epd = [&](int dst, const f32x4& ev) {
    bf16x4 h4, l4;
    #pragma unroll
    for (int j = 0; j < 4; ++j) { __bf16 h, l; split_bf16(ev[j], h, l); h4[j] = h; l4[j] = l; }
    char* p0 = sm + 8192 + dst * 4096;
    const int off = pk_off(sb, so);
    *(bf16x4*)(p0 + off) = h4;
    *(bf16x4*)(p0 + 2048 + off) = l4;
  };
  auto put_gi = [&](int dst, const f32x4& a0, const f32x4& a1, const f32x4& a2) {
    float* gw = (float*)(sm + 16384 + dst * 16640);
    const int gc = aw * 16 + fr;
    #pragma unroll
    for (int e = 0; e < 4; ++e) {
      f32x4 o = (f32x4){a0[e] + bR_, a1[e] + bZ_, a2[e] + bN_, 0.f};
      *(f32x4*)(gw + (q * 4 + e) * 260 + gc * 4) = o;
    }
  };

  for (int rep = 0; rep < REPS; ++rep) {
    float hreg[4] = {0.f, 0.f, 0.f, 0.f};
    if (isB) {
      #pragma unroll
      for (int e = 0; e < 4; ++e)
        hreg[e] = h0g[(size_t)(bbase + q * 4 + e) * 64 + hcol];
    }
    f32x4 evA = (f32x4){0.f,0.f,0.f,0.f}, evB = evA, e1v = evA;
    if (isB) {
      char* h0b = sm;
      char* h1b = sm + 2048;
      #pragma unroll
      for (int e = 0; e < 4; ++e) {
        __bf16 h, l; split_bf16(hreg[e], h, l);
        const int off = pk_off(q * 4 + e, hcol);
        *(__bf16*)(h0b + off) = h;
        *(__bf16*)(h1b + off) = l;
      }
    } else {
      const float* eb = enc + (size_t)(bbase + sb) * 64 * 64 + so;
      f32x4 e0v = *(const f32x4*)(eb);
      e1v = *(const f32x4*)(eb + 64);
      evA = *(const f32x4*)(eb + 2 * 64);
      evB = *(const f32x4*)(eb + 3 * 64);
      put_epd(1, e0v);
    }
    bar_lds();
    if (!isB) {
      f32x4 a0 = (f32x4){0.f,0.f,0.f,0.f}, a1 = a0, a2 = a0;
      gate_mfma(sm + 8192 + 1 * 4096, a0, a1, a2);
      put_gi(0, a0, a1, a2);
      put_epd(0, e1v);
    }
    bar_lds();

    auto body = [&](int t, int cur, f32x4& evC) {
      f32x4 a0 = (f32x4){0.f,0.f,0.f,0.f}, a1 = a0, a2 = a0;
      float giN[4];
      const char* s0;
      if (isB) {
        const float* gr = (const float*)(sm + 16384 + cur * 16640);
        #pragma unroll
        for (int e = 0; e < 4; ++e) {
          f32x4 gv = *(const f32x4*)(gr + (q * 4 + e) * 260 + hcol * 4);
          a0[e] = gv[0]; a1[e] = gv[1]; giN[e] = gv[2];
        }
        s0 = sm + cur * 4096;
      } else {
        s0 = sm + 8192 + cur * 4096;
      }
      const bool doMain = isB ? (t <= 63) : (t <= 62);
      if (doMain) gate_mfma(s0, a0, a1, a2);

      if (isB) {
        if (t <= 63) {
          char* n0 = sm + (cur ^ 1) * 4096;
          char* n1 = n0 + 2048;
          #pragma unroll
          for (int e = 0; e < 4; ++e) {
            const float rr = 1.f / (1.f + __expf(-a0[e]));
            const float zz = 1.f / (1.f + __expf(-a1[e]));
            const float npre = giN[e] + rr * (a2[e] + biasNh);
            const float nn = 2.f / (1.f + __expf(-2.f * npre)) - 1.f;
            const float hv = (1.f - zz) * nn + zz * hreg[e];
            hreg[e] = hv;
            hout[((size_t)(bbase + q * 4 + e) * 64 + t) * 64 + hcol] = hv;
            __bf16 h, l; split_bf16(hv, h, l);
            const int off = pk_off(q * 4 + e, hcol);
            *(__bf16*)(n0 + off) = h;
            *(__bf16*)(n1 + off) = l;
          }
        }
      } else {
        if (t <= 62) put_gi(cur ^ 1, a0, a1, a2);
        if (t >= 1 && t <= 64 && aw < 3) {
          const char* hp0c = sm + cur * 4096;
          const char* hp1c = hp0c + 2048;
          bf16x8 Hh[2], Hl[2];
          #pragma unroll
          for (int kk = 0; kk < 2; ++kk) {
            Hh[kk] = frag_pk(hp0c, fr, kk, q);
            Hl[kk] = frag_pk(hp1c, fr, kk, q);
          }
          f32x4 lacc = (f32x4){0.f, 0.f, 0.f, 0.f};
          #pragma unroll
          for (int kk = 0; kk < 2; ++kk) {
            lacc = MFMA16(Hh[kk], Fout[kk][0], lacc, 0, 0, 0);
            lacc = MFMA16(Hh[kk], Fout[kk][1], lacc, 0, 0, 0);
            lacc = MFMA16(Hl[kk], Fout[kk][0], lacc, 0, 0, 0);
          }
          float* lg = (float*)(sm + 49664 + (cur ^ 1) * 3072);
          #pragma unroll
          for (int e = 0; e < 4; ++e)
            lg[(q * 4 + e) * 48 + aw * 16 + fr] = lacc[e] + boutv;
        }
        if (t <= 61) put_epd(cur ^ 1, evC);
        if (t <= 59)
          evC = *(const f32x4*)(enc + ((size_t)(bbase + sb) * 64 + (t + 4)) * 64 + so);
        if (t >= 2) {
          const float* lg = (const float*)(sm + 49664 + cur * 3072);
          const float e0 = __expf(lg[sb * 48 + sub]);
          const float e1 = (sub + 16 < 45) ? __expf(lg[sb * 48 + sub + 16]) : 0.f;
          const float e2 = (sub + 32 < 45) ? __expf(lg[sb * 48 + sub + 32]) : 0.f;
          float s = e0 + e1 + e2;
          s += __shfl_xor(s, 1, 16);
          s += __shfl_xor(s, 2, 16);
          s += __shfl_xor(s, 4, 16);
          s += __shfl_xor(s, 8, 16);
          if (s <= TINY_THR) s = 1.f;
          const float sc  = (1.f - epsv) / s;
          const float bse = epsv * (1.f / 45.f);
          float* orow = xout + ((size_t)(bbase + sb) * 64 + (t - 2)) * 45;
          orow[sub] = bse + e0 * sc;
          if (sub + 16 < 45) orow[sub + 16] = bse + e1 * sc;
          if (sub + 32 < 45) orow[sub + 32] = bse + e2 * sc;
        }
      }
      bar_lds();
    };

    for (int t2 = 0; t2 < 66; t2 += 2) {
      body(t2, 0, evA);
      body(t2 + 1, 1, evB);
    }
  }
}

extern "C" void kernel_launch(void* const* d_in, const int* in_sizes, int n_in,
                              void* d_out, int out_size, void* d_ws, size_t ws_size,
                              hipStream_t stream) {
  (void)in_sizes; (void)n_in; (void)out_size; (void)ws_size;
  const float* x    = (const float*)d_in[0];
  const float* h0   = (const float*)d_in[1];
  const float* eps  = (const float*)d_in[2];
  const float* Wfc  = (const float*)d_in[3];
  const float* bfc  = (const float*)d_in[4];
  const float* Wih  = (const float*)d_in[5];
  const float* Whh  = (const float*)d_in[6];
  const float* bih  = (const float*)d_in[7];
  const float* bhh  = (const float*)d_in[8];
  const float* Wout = (const float*)d_in[9];
  const float* bout = (const float*)d_in[10];

  float* xout = (float*)d_out;
  float* hout = xout + XOUT_N;
  float* enc = hout;           // enc aliases h_out (consumed-before-overwrite)
  __bf16* Wpk = (__bf16*)d_out;  // 128 KB alias of xout, consumed before k_scan

  k_prepW<<<128, 256, 0, stream>>>(Wfc, Wpk);
  k_encgemm<<<4096, 256, 0, stream>>>(x, Wpk, bfc, enc);
  k_scan<1><<<256, 512, 0, stream>>>(enc, h0, eps, Wih, Whh, bih, bhh, Wout,
                                     bout, xout, hout);
  // ---- PMC instrumentation: 6x-looped scan into scratch (top-5 visible) ----
  float* xout_d = (float*)d_ws;
  float* hout_d = xout_d + XOUT_N;
  k_scan<6><<<256, 512, 0, stream>>>(enc, h0, eps, Wih, Whh, bih, bhh, Wout,
                                     bout, xout_d, hout_d);
}

// Round 8
// 237.232 us; speedup vs baseline: 3.2971x; 3.2971x over previous
//
#include <hip/hip_runtime.h>

typedef __attribute__((ext_vector_type(4))) float  f32x4;
typedef __attribute__((ext_vector_type(4))) __bf16 bf16x4;
typedef __attribute__((ext_vector_type(8))) __bf16 bf16x8;

#define MFMA16 __builtin_amdgcn_mfma_f32_16x16x32_bf16
#define TINY_THR 4.8789098e-18f
#define XOUT_N ((size_t)4096 * 64 * 45)

__device__ __forceinline__ void bar_lds() {
  asm volatile("s_waitcnt lgkmcnt(0)\n\ts_barrier" ::: "memory");
}
__device__ __forceinline__ void split_bf16(float v, __bf16& h, __bf16& l) {
  h = (__bf16)v; l = (__bf16)(v - (float)h);
}
__device__ __forceinline__ void gll16(const void* g, void* l) {
  __builtin_amdgcn_global_load_lds(
      (const __attribute__((address_space(1))) void*)g,
      (__attribute__((address_space(3))) void*)l, 16, 0, 0);
}

// Packed+swizzled bf16 tile [rows][64 cols], 128 B/row, 8 blocks of 16 B.
__device__ __forceinline__ int pk_off(int row, int col) {
  const int kk = col >> 5, rem = col & 31;
  const int half = rem >> 4, qq = (rem >> 2) & 3, j = rem & 3;
  return row * 128 + ((((kk << 2) | qq) ^ (row & 7)) << 4) + half * 8 + j * 2;
}
__device__ __forceinline__ bf16x8 frag_pk(const char* base, int row, int kk, int qq) {
  return *(const bf16x8*)(base + row * 128 + ((((kk << 2) | qq) ^ (row & 7)) << 4));
}

// ---------------------------------------------------------------------------
// Kernel 0: prepack W_fc1 (unchanged)
// ---------------------------------------------------------------------------
__global__ void k_prepW(const float* __restrict__ Wfc, __bf16* __restrict__ Wpk) {
  const int idx = blockIdx.x * 256 + threadIdx.x;  // 32768 total
  const float v = Wfc[idx];
  __bf16 h, l; split_bf16(v, h, l);
  const int row = idx >> 9, k = idx & 511;
  const int c = k >> 6, kl = k & 63;
  const int kk = kl >> 5, rem = kl & 31;
  const int half = rem >> 4, q = (rem >> 2) & 3, j = rem & 3;
  const int blk = ((kk << 2) | q) ^ (row & 7);
  const int pos = c * 8192 + row * 64 + blk * 8 + half * 4 + j;
  Wpk[pos] = h;
  Wpk[pos + 4096] = l;
}

// ---------------------------------------------------------------------------
// Kernel 1: relu(x . W_fc1^T + b) -> bf16 hi/lo PAIRS, written directly in
// the pk-tile layout k_scan stages with global_load_lds:
//   tile (bg = b>>4, t): 4 KB = [hi 2KB | lo 2KB], row r = b&15, pk_off cols.
// Main loop unchanged from R7. No f32 enc output at all.
// ---------------------------------------------------------------------------
__global__ __launch_bounds__(256, 2) void k_encgemm(
    const float* __restrict__ x, const __bf16* __restrict__ Wpk,
    const float* __restrict__ bfc, __bf16* __restrict__ pairs) {
  __shared__ __attribute__((aligned(16))) char sm[65536];
  const int tid  = threadIdx.x;
  const int lane = tid & 63;
  const int wv   = tid >> 6;
  const int fr   = lane & 15;
  const int q    = lane >> 4;
  const int b    = blockIdx.x;

  auto stage = [&](int c, int buf) {
    char* xbase = sm + buf * 16384;
    char* wbase = sm + 32768 + buf * 16384;
    #pragma unroll
    for (int i = 0; i < 4; ++i) {
      const int B   = wv * 256 + i * 64 + lane;
      const int row = B >> 4, blk = B & 15;
      const int bp  = blk ^ (row & 15);
      const int colb = ((bp >> 3) << 5) | ((bp & 1) << 4) | (((bp >> 1) & 3) << 2);
      const float* src = x + ((size_t)b * 64 + row) * 512 + c * 64 + colb;
      gll16(src, xbase + wv * 4096 + i * 1024);
    }
    #pragma unroll
    for (int i = 0; i < 4; ++i) {
      const __bf16* srcw = Wpk + c * 8192 + wv * 2048 + i * 512 + lane * 8;
      gll16(srcw, wbase + wv * 4096 + i * 1024);
    }
  };

  f32x4 acc[4];
  #pragma unroll
  for (int nt = 0; nt < 4; ++nt) acc[nt] = (f32x4){0.f, 0.f, 0.f, 0.f};

  stage(0, 0);
  int buf = 0;
  for (int c = 0; c < 8; ++c) {
    if (c < 7) {
      stage(c + 1, buf ^ 1);
      asm volatile("s_waitcnt vmcnt(8)\n\ts_barrier" ::: "memory");
    } else {
      asm volatile("s_waitcnt vmcnt(0)\n\ts_barrier" ::: "memory");
    }
    const char* xbase = sm + buf * 16384;
    const char* wbase = sm + 32768 + buf * 16384;
    const int arow = wv * 16 + fr;
    bf16x8 Ah[2], Al[2];
    #pragma unroll
    for (int kk = 0; kk < 2; ++kk) {
      f32x4 u0 = *(const f32x4*)(xbase + arow * 256 + (((kk * 8 + q * 2 + 0) ^ (arow & 15)) << 4));
      f32x4 u1 = *(const f32x4*)(xbase + arow * 256 + (((kk * 8 + q * 2 + 1) ^ (arow & 15)) << 4));
      #pragma unroll
      for (int j = 0; j < 4; ++j) {
        __bf16 h, l;
        split_bf16(u0[j], h, l); Ah[kk][j] = h;     Al[kk][j] = l;
        split_bf16(u1[j], h, l); Ah[kk][4 + j] = h; Al[kk][4 + j] = l;
      }
    }
    #pragma unroll
    for (int nt = 0; nt < 4; ++nt) {
      const int brow = nt * 16 + fr;
      #pragma unroll
      for (int kk = 0; kk < 2; ++kk) {
        bf16x8 Bh = frag_pk(wbase, brow, kk, q);
        bf16x8 Bl = frag_pk(wbase + 8192, brow, kk, q);
        acc[nt] = MFMA16(Ah[kk], Bh, acc[nt], 0, 0, 0);
        acc[nt] = MFMA16(Ah[kk], Bl, acc[nt], 0, 0, 0);
        acc[nt] = MFMA16(Al[kk], Bh, acc[nt], 0, 0, 0);
      }
    }
    bar_lds();
    buf ^= 1;
  }
  // epilogue: bounce to LDS f32, then split+store bf16 pairs in pk layout.
  float* ep = (float*)(sm + wv * 4352);  // 16 rows x 68 f32, wave-private
  #pragma unroll
  for (int nt = 0; nt < 4; ++nt) {
    const int o = nt * 16 + fr;
    const float bb = bfc[o];
    #pragma unroll
    for (int e = 0; e < 4; ++e)
      ep[(q * 4 + e) * 68 + o] = fmaxf(acc[nt][e] + bb, 0.f);
  }
  asm volatile("s_waitcnt lgkmcnt(0)" ::: "memory");
  const int r = b & 15;
  const size_t bgbase = (size_t)(b >> 4) * 64 * 4096;
  #pragma unroll
  for (int r2 = 0; r2 < 4; ++r2) {
    const int row = (lane >> 4) + 4 * r2;  // t-local row
    const int cg  = lane & 15;             // cols cg*4 .. cg*4+3
    f32x4 v = *(const f32x4*)(ep + row * 68 + cg * 4);
    bf16x4 hi4, lo4;
    #pragma unroll
    for (int j = 0; j < 4; ++j) {
      __bf16 h, l; split_bf16(v[j], h, l); hi4[j] = h; lo4[j] = l;
    }
    const int blk  = ((((cg >> 3) << 2) | (cg & 3)) ^ (r & 7));
    const int boff = r * 128 + (blk << 4) + ((cg >> 2) & 1) * 8;
    char* dst = (char*)pairs + bgbase + (size_t)(wv * 16 + row) * 4096 + boff;
    *(bf16x4*)dst = hi4;            // hi plane
    *(bf16x4*)(dst + 2048) = lo4;   // lo plane
  }
}

// ---------------------------------------------------------------------------
// Kernel 2: fused GRU scan. A-waves now stage epd tiles via global_load_lds
// from the pre-split pair buffer (no per-iter f32 loads / splits), counted
// vmcnt before the end-of-iter barrier. Softmax pad cols use -1e30 bout.
// smem: hp buf*4096 | epd 8192+buf*4096 | gi 16384+buf*16640 | lgt
// 49664+buf*3072 | wstage init alias [0,49152).
// ---------------------------------------------------------------------------
__global__ __launch_bounds__(512, 1) void k_scan(
    const __bf16* __restrict__ pairs, const float* __restrict__ h0g,
    const float* __restrict__ eps, const float* __restrict__ Wih,
    const float* __restrict__ Whh, const float* __restrict__ bih,
    const float* __restrict__ bhh, const float* __restrict__ Wout,
    const float* __restrict__ bout, float* __restrict__ xout,
    float* __restrict__ hout) {
  __shared__ __attribute__((aligned(16))) char sm[55808];
  char* const wst0 = sm;
  char* const wst1 = sm + 24576;

  const int tid  = threadIdx.x;
  const int lane = tid & 63;
  const int wv   = tid >> 6;
  const int fr   = lane & 15;
  const int q    = lane >> 4;
  const int bbase = blockIdx.x * 16;
  const bool isB = (wv < 4);
  const int aw  = wv - 4;
  const int at  = tid & 255;
  const int sb  = at >> 4;
  const int sub = at & 15;

  float biasNh = 0.f;
  int hcol = 0;
  float boutv = 0.f, epsv = 0.f;
  if (isB) {
    hcol = wv * 16 + fr;
    biasNh = bhh[128 + hcol];
  } else {
    const int gc = aw * 16 + fr;
    if (aw < 3) boutv = (gc < 45) ? bout[gc] : -1e30f;
    epsv = eps[bbase + sb];
  }
  float bR_ = 0.f, bZ_ = 0.f, bN_ = 0.f;
  if (!isB) {
    const int gc = aw * 16 + fr;
    bR_ = bih[gc] + bhh[gc];
    bZ_ = bih[64 + gc] + bhh[64 + gc];
    bN_ = bih[128 + gc];
  }

  bf16x8 Fh[3][2], Fl[3][2];
  bf16x8 Fout[2][2];

  for (int idx = tid; idx < 192 * 64; idx += 512) {
    __bf16 h, l; split_bf16(Wih[idx], h, l);
    const int off = pk_off(idx >> 6, idx & 63);
    *(__bf16*)(wst0 + off) = h;
    *(__bf16*)(wst1 + off) = l;
  }
  bar_lds();
  if (!isB) {
    #pragma unroll
    for (int t3 = 0; t3 < 3; ++t3)
      #pragma unroll
      for (int kk = 0; kk < 2; ++kk) {
        const int row = (aw + 4 * t3) * 16 + fr;
        Fh[t3][kk] = frag_pk(wst0, row, kk, q);
        Fl[t3][kk] = frag_pk(wst1, row, kk, q);
      }
  }
  bar_lds();
  for (int idx = tid; idx < 192 * 64; idx += 512) {
    __bf16 h, l; split_bf16(Whh[idx], h, l);
    const int off = pk_off(idx >> 6, idx & 63);
    *(__bf16*)(wst0 + off) = h;
    *(__bf16*)(wst1 + off) = l;
  }
  bar_lds();
  if (isB) {
    #pragma unroll
    for (int t3 = 0; t3 < 3; ++t3)
      #pragma unroll
      for (int kk = 0; kk < 2; ++kk) {
        const int row = (wv + 4 * t3) * 16 + fr;
        Fh[t3][kk] = frag_pk(wst0, row, kk, q);
        Fl[t3][kk] = frag_pk(wst1, row, kk, q);
      }
  }
  bar_lds();
  for (int idx = tid; idx < 48 * 64; idx += 512) {
    float v = (idx < 45 * 64) ? Wout[idx] : 0.f;
    __bf16 h, l; split_bf16(v, h, l);
    const int off = pk_off(idx >> 6, idx & 63);
    *(__bf16*)(wst0 + off) = h;
    *(__bf16*)(wst1 + off) = l;
  }
  bar_lds();
  if (!isB && aw < 3) {
    #pragma unroll
    for (int kk = 0; kk < 2; ++kk) {
      const int row = aw * 16 + fr;
      Fout[kk][0] = frag_pk(wst0, row, kk, q);
      Fout[kk][1] = frag_pk(wst1, row, kk, q);
    }
  }
  bar_lds();  // wstage free -> runtime buffers live

  auto gate_mfma = [&](const char* s0, f32x4& a0, f32x4& a1, f32x4& a2) {
    const char* s1 = s0 + 2048;
    bf16x8 Sh[2], Sl[2];
    #pragma unroll
    for (int kk = 0; kk < 2; ++kk) {
      Sh[kk] = frag_pk(s0, fr, kk, q);
      Sl[kk] = frag_pk(s1, fr, kk, q);
    }
    __builtin_amdgcn_s_setprio(1);
    #pragma unroll
    for (int kk = 0; kk < 2; ++kk) {
      a0 = MFMA16(Sh[kk], Fh[0][kk], a0, 0, 0, 0);
      a0 = MFMA16(Sh[kk], Fl[0][kk], a0, 0, 0, 0);
      a0 = MFMA16(Sl[kk], Fh[0][kk], a0, 0, 0, 0);
      a1 = MFMA16(Sh[kk], Fh[1][kk], a1, 0, 0, 0);
      a1 = MFMA16(Sh[kk], Fl[1][kk], a1, 0, 0, 0);
      a1 = MFMA16(Sl[kk], Fh[1][kk], a1, 0, 0, 0);
      a2 = MFMA16(Sh[kk], Fh[2][kk], a2, 0, 0, 0);
      a2 = MFMA16(Sh[kk], Fl[2][kk], a2, 0, 0, 0);
      a2 = MFMA16(Sl[kk], Fh[2][kk], a2, 0, 0, 0);
    }
    __builtin_amdgcn_s_setprio(0);
  };
  // A-wave: async-stage one 4KB pk tile (time tt) into epd[dst] via gll16.
  auto stage_epd = [&](int dst, int tt) {
    const char* src = (const char*)pairs +
        ((size_t)blockIdx.x * 64 + tt) * 4096 + (at >> 7) * 2048 + (at & 127) * 16;
    char* dl = sm + 8192 + dst * 4096 + (at >> 7) * 2048 + (at & 127) * 16;
    gll16(src, dl);
  };
  auto put_gi = [&](int dst, const f32x4& a0, const f32x4& a1, const f32x4& a2) {
    float* gw = (float*)(sm + 16384 + dst * 16640);
    const int gc = aw * 16 + fr;
    #pragma unroll
    for (int e = 0; e < 4; ++e) {
      f32x4 o = (f32x4){a0[e] + bR_, a1[e] + bZ_, a2[e] + bN_, 0.f};
      *(f32x4*)(gw + (q * 4 + e) * 260 + gc * 4) = o;
    }
  };

  float hreg[4] = {0.f, 0.f, 0.f, 0.f};
  if (isB) {
    #pragma unroll
    for (int e = 0; e < 4; ++e)
      hreg[e] = h0g[(size_t)(bbase + q * 4 + e) * 64 + hcol];
    char* h0b = sm;
    char* h1b = sm + 2048;
    #pragma unroll
    for (int e = 0; e < 4; ++e) {
      __bf16 h, l; split_bf16(hreg[e], h, l);
      const int off = pk_off(q * 4 + e, hcol);
      *(__bf16*)(h0b + off) = h;
      *(__bf16*)(h1b + off) = l;
    }
  } else {
    stage_epd(1, 0);   // epd[1] <- enc[0]
    stage_epd(0, 1);   // epd[0] <- enc[1]
    asm volatile("s_waitcnt vmcnt(0)" ::: "memory");
  }
  bar_lds();
  if (!isB) {
    f32x4 a0 = (f32x4){0.f,0.f,0.f,0.f}, a1 = a0, a2 = a0;
    gate_mfma(sm + 8192 + 1 * 4096, a0, a1, a2);  // gi[0] from enc[0]
    put_gi(0, a0, a1, a2);
  }
  bar_lds();

  auto body = [&](int t, int cur) {
    f32x4 a0 = (f32x4){0.f,0.f,0.f,0.f}, a1 = a0, a2 = a0;
    float giN[4];
    if (isB) {
      if (t <= 63) {
        const float* gr = (const float*)(sm + 16384 + cur * 16640);
        #pragma unroll
        for (int e = 0; e < 4; ++e) {
          f32x4 gv = *(const f32x4*)(gr + (q * 4 + e) * 260 + hcol * 4);
          a0[e] = gv[0]; a1[e] = gv[1]; giN[e] = gv[2];
        }
        gate_mfma(sm + cur * 4096, a0, a1, a2);
        char* n0 = sm + (cur ^ 1) * 4096;
        char* n1 = n0 + 2048;
        #pragma unroll
        for (int e = 0; e < 4; ++e) {
          const float rr = 1.f / (1.f + __expf(-a0[e]));
          const float zz = 1.f / (1.f + __expf(-a1[e]));
          const float npre = giN[e] + rr * (a2[e] + biasNh);
          const float nn = 2.f / (1.f + __expf(-2.f * npre)) - 1.f;
          const float hv = (1.f - zz) * nn + zz * hreg[e];
          hreg[e] = hv;
          hout[((size_t)(bbase + q * 4 + e) * 64 + t) * 64 + hcol] = hv;
          __bf16 h, l; split_bf16(hv, h, l);
          const int off = pk_off(q * 4 + e, hcol);
          *(__bf16*)(n0 + off) = h;
          *(__bf16*)(n1 + off) = l;
        }
      }
    } else {
      if (t <= 61) stage_epd(cur ^ 1, t + 2);  // async; consumed next iter
      if (t <= 62) {
        gate_mfma(sm + 8192 + cur * 4096, a0, a1, a2);
        put_gi(cur ^ 1, a0, a1, a2);
      }
      if (t >= 1 && t <= 64 && aw < 3) {
        const char* hp0c = sm + cur * 4096;
        const char* hp1c = hp0c + 2048;
        bf16x8 Hh[2], Hl[2];
        #pragma unroll
        for (int kk = 0; kk < 2; ++kk) {
          Hh[kk] = frag_pk(hp0c, fr, kk, q);
          Hl[kk] = frag_pk(hp1c, fr, kk, q);
        }
        f32x4 lacc = (f32x4){0.f, 0.f, 0.f, 0.f};
        #pragma unroll
        for (int kk = 0; kk < 2; ++kk) {
          lacc = MFMA16(Hh[kk], Fout[kk][0], lacc, 0, 0, 0);
          lacc = MFMA16(Hh[kk], Fout[kk][1], lacc, 0, 0, 0);
          lacc = MFMA16(Hl[kk], Fout[kk][0], lacc, 0, 0, 0);
        }
        float* lg = (float*)(sm + 49664 + (cur ^ 1) * 3072);
        #pragma unroll
        for (int e = 0; e < 4; ++e)
          lg[(q * 4 + e) * 48 + aw * 16 + fr] = lacc[e] + boutv;
      }
      if (t >= 2) {
        const float* lg = (const float*)(sm + 49664 + cur * 3072);
        const float e0 = __expf(lg[sb * 48 + sub]);
        const float e1 = __expf(lg[sb * 48 + sub + 16]);
        const float e2 = __expf(lg[sb * 48 + sub + 32]);   // pad cols -> 0
        float s = e0 + e1 + e2;
        s += __shfl_xor(s, 1, 16);
        s += __shfl_xor(s, 2, 16);
        s += __shfl_xor(s, 4, 16);
        s += __shfl_xor(s, 8, 16);
        if (s <= TINY_THR) s = 1.f;
        const float sc  = (1.f - epsv) / s;
        const float bse = epsv * (1.f / 45.f);
        float* orow = xout + ((size_t)(bbase + sb) * 64 + (t - 2)) * 45;
        orow[sub] = bse + e0 * sc;
        orow[sub + 16] = bse + e1 * sc;
        if (sub < 13) orow[sub + 32] = bse + e2 * sc;
      }
      if (t <= 61) {  // publish this iter's gll16 before the barrier
        if (t >= 2) asm volatile("s_waitcnt vmcnt(3)" ::: "memory");
        else        asm volatile("s_waitcnt vmcnt(0)" ::: "memory");
      }
    }
    bar_lds();
  };

  for (int t2 = 0; t2 < 66; t2 += 2) {
    body(t2, 0);
    body(t2 + 1, 1);
  }
}

extern "C" void kernel_launch(void* const* d_in, const int* in_sizes, int n_in,
                              void* d_out, int out_size, void* d_ws, size_t ws_size,
                              hipStream_t stream) {
  (void)in_sizes; (void)n_in; (void)out_size; (void)ws_size;
  const float* x    = (const float*)d_in[0];
  const float* h0   = (const float*)d_in[1];
  const float* eps  = (const float*)d_in[2];
  const float* Wfc  = (const float*)d_in[3];
  const float* bfc  = (const float*)d_in[4];
  const float* Wih  = (const float*)d_in[5];
  const float* Whh  = (const float*)d_in[6];
  const float* bih  = (const float*)d_in[7];
  const float* bhh  = (const float*)d_in[8];
  const float* Wout = (const float*)d_in[9];
  const float* bout = (const float*)d_in[10];

  float* xout = (float*)d_out;
  float* hout = xout + XOUT_N;
  // pre-split enc pair tiles (64 MB) live in scratch; fully rewritten by
  // k_encgemm before k_scan reads them -> deterministic across replays.
  __bf16* pairs = (__bf16*)d_ws;
  // Wpk (128 KB) aliases start of xout; consumed before k_scan writes xout.
  __bf16* Wpk = (__bf16*)d_out;

  k_prepW<<<128, 256, 0, stream>>>(Wfc, Wpk);
  k_encgemm<<<4096, 256, 0, stream>>>(x, Wpk, bfc, pairs);
  k_scan<<<256, 512, 0, stream>>>(pairs, h0, eps, Wih, Whh, bih, bhh, Wout,
                                  bout, xout, hout);
}